// Round 2
// baseline (5618.592 us; speedup 1.0000x reference)
//
#include <hip/hip_runtime.h>

// WaveNet decoder for MI355X (gfx950).
//   - activations stored TRANSPOSED: h[t][c] (t-major, c contiguous)
//   - h kept as fp32 master (in-place, block-exclusive t-rows) plus fp16
//     ping/pong copies (GEMM input; ping/pong avoids cross-block RAW race in
//     the dilated conv which reads other blocks' t-rows).
//   - ALL GEMM operands in fp16 (not bf16): 4x smaller rounding error at the
//     same MFMA rate; everything here is well inside fp16 range.
//   - weights pre-converted to fp16; w_dil transposed to [layer][tap][m][c].
//   - cond (w_cond@emb + b_cond + b_dil) precomputed per layer: [1024][32].

typedef _Float16 f16x8 __attribute__((ext_vector_type(8)));
typedef float f32x4 __attribute__((ext_vector_type(4)));
typedef unsigned int u32x4 __attribute__((ext_vector_type(4)));

#define NSTACK 30
#define TLEN   16384

__device__ __forceinline__ unsigned short f2h(float x) {
  union { _Float16 h; unsigned short u; } c;
  c.h = (_Float16)x;                       // v_cvt_f16_f32, RNE
  return c.u;
}
__device__ __forceinline__ unsigned pack2(float a, float b) {
  return (unsigned)f2h(a) | ((unsigned)f2h(b) << 16);
}
__device__ __forceinline__ f16x8 ldh(const unsigned short* p) {
  return *(const f16x8*)p;
}
__device__ __forceinline__ f16x8 ldh_guard(const unsigned short* p, bool ok) {
  union { u32x4 u; f16x8 v; } x;
  if (ok) { x.u = *(const u32x4*)p; }
  else    { x.u[0]=0u; x.u[1]=0u; x.u[2]=0u; x.u[3]=0u; }
  return x.v;
}
__device__ __forceinline__ float sigmoidf_(float x){ return 1.0f/(1.0f+__expf(-x)); }
__device__ __forceinline__ float tanhf_(float x){ return 1.0f - 2.0f/(__expf(2.0f*x)+1.0f); }

// ---------------- small prep kernels ----------------

__global__ void cast_f16_kernel(const float* __restrict__ src,
                                unsigned short* __restrict__ dst, int n4) {
  int g = blockIdx.x*256 + threadIdx.x;
  if (g >= n4) return;
  f32x4 v = *(const f32x4*)(src + 4*(size_t)g);
  unsigned int* d = (unsigned int*)(dst + 4*(size_t)g);
  d[0] = pack2(v[0], v[1]);
  d[1] = pack2(v[2], v[3]);
}

// w_dil [30][1024][512][3] f32 -> A_dil [30][3][1024][512] fp16
__global__ void transpose_wdil_kernel(const float* __restrict__ src,
                                      unsigned short* __restrict__ dst) {
  int g = blockIdx.x*256 + threadIdx.x;       // over 30*1024*512
  if (g >= NSTACK*1024*512) return;
  int c = g & 511;
  int m = (g >> 9) & 1023;
  int i = g >> 19;
  const float* s = src + (size_t)g*3;
  #pragma unroll
  for (int tap=0; tap<3; ++tap)
    dst[(((size_t)i*3+tap)*1024 + m)*512 + c] = f2h(s[tap]);
}

// cond_all[i][m][e] = b_cond[i][m] + b_dil[i][m] + sum_c w_cond[i][m][c]*emb[c][e]
// fcond_all[m][e]   = b_fcond[m] + sum_c w_fcond[m][c]*emb[c][e]
__global__ void cond_kernel(const float* __restrict__ emb,
                            const float* __restrict__ w_cond, const float* __restrict__ b_cond,
                            const float* __restrict__ b_dil,
                            const float* __restrict__ w_fcond, const float* __restrict__ b_fcond,
                            float* __restrict__ cond_all, float* __restrict__ fcond_all) {
  int g = blockIdx.x*256 + threadIdx.x;
  if (g < NSTACK*1024) {
    float acc[32];
    float base = b_cond[g] + b_dil[g];
    #pragma unroll
    for (int e=0;e<32;++e) acc[e] = base;
    #pragma unroll
    for (int c=0;c<16;++c) {
      float wv = w_cond[(size_t)g*16 + c];
      #pragma unroll
      for (int e=0;e<32;++e) acc[e] += wv * emb[c*32+e];
    }
    #pragma unroll
    for (int e=0;e<32;++e) cond_all[(size_t)g*32+e] = acc[e];
  } else if (g < NSTACK*1024 + 256) {
    int m = g - NSTACK*1024;
    float acc[32];
    float base = b_fcond[m];
    #pragma unroll
    for (int e=0;e<32;++e) acc[e] = base;
    #pragma unroll
    for (int c=0;c<16;++c) {
      float wv = w_fcond[(size_t)m*16 + c];
      #pragma unroll
      for (int e=0;e<32;++e) acc[e] += wv * emb[c*32+e];
    }
    #pragma unroll
    for (int e=0;e<32;++e) fcond_all[(size_t)m*32+e] = acc[e];
  }
}

// h0[t][c] = causal k3 conv of x, + b_init. Writes fp32 master + fp16 ping.
__global__ void h0_kernel(const float* __restrict__ x, const float* __restrict__ w_init,
                          const float* __restrict__ b_init,
                          float* __restrict__ h_f32, unsigned short* __restrict__ h_h16) {
  int g = blockIdx.x*256 + threadIdx.x;   // exactly 16384*128
  int t = g >> 7;
  int c = (g & 127) << 2;
  float xm2 = (t>=2)? x[t-2] : 0.f;
  float xm1 = (t>=1)? x[t-1] : 0.f;
  float x0  = x[t];
  f32x4 hv;
  #pragma unroll
  for (int r=0;r<4;++r) {
    int cc = c + r;
    hv[r] = w_init[cc*3+0]*xm2 + w_init[cc*3+1]*xm1 + w_init[cc*3+2]*x0 + b_init[cc];
  }
  *(f32x4*)&h_f32[(size_t)t*512 + c] = hv;
  unsigned int* hb = (unsigned int*)&h_h16[(size_t)t*512 + c];
  hb[0] = pack2(hv[0],hv[1]); hb[1] = pack2(hv[2],hv[3]);
}

// skip[t][s] = W_iskip @ h0 + b_iskip   (M=256,K=512,N=16384)
__global__ __launch_bounds__(512) void skip_init_kernel(
    const unsigned short* __restrict__ h_h16, const unsigned short* __restrict__ Wiskip,
    const float* __restrict__ b_iskip, float* __restrict__ skip_f32) {
  int tid=threadIdx.x, w=tid>>6, l=tid&63, lr=l&15, lc=l>>4;
  int tb = blockIdx.x<<6;
  f32x4 acc[2][4];
  #pragma unroll
  for (int mf=0;mf<2;++mf)
    #pragma unroll
    for (int nf=0;nf<4;++nf) acc[mf][nf] = {0.f,0.f,0.f,0.f};
  for (int kc=0;kc<512;kc+=32) {
    f16x8 b[4];
    #pragma unroll
    for (int nf=0;nf<4;++nf)
      b[nf] = ldh(&h_h16[(size_t)(tb+16*nf+lr)*512 + kc + lc*8]);
    #pragma unroll
    for (int mf=0;mf<2;++mf) {
      f16x8 a = ldh(&Wiskip[(size_t)(w*32+16*mf+lr)*512 + kc + lc*8]);
      #pragma unroll
      for (int nf=0;nf<4;++nf)
        acc[mf][nf] = __builtin_amdgcn_mfma_f32_16x16x32_f16(a, b[nf], acc[mf][nf], 0,0,0);
    }
  }
  #pragma unroll
  for (int mf=0;mf<2;++mf)
    #pragma unroll
    for (int nf=0;nf<4;++nf) {
      int s0 = w*32+16*mf+4*lc;
      int t  = tb+16*nf+lr;
      f32x4 v;
      #pragma unroll
      for (int r=0;r<4;++r) v[r] = acc[mf][nf][r] + b_iskip[s0+r];
      *(f32x4*)&skip_f32[(size_t)t*256+s0] = v;
    }
}

// ---------------- the fused per-layer kernel ----------------
// Block: 64 t-columns, full M. 8 waves; wave w owns filter rows [64w,64w+64)
// and gate rows [512+64w, 512+64w+64) -> gating is wave-local.
__global__ __launch_bounds__(512) void layer_kernel(
    const unsigned short* __restrict__ h_in,    // [T][512] fp16 ping
    unsigned short* __restrict__ h_out,         // [T][512] fp16 pong
    float* __restrict__ h_f32,                  // [T][512] f32 master (in-place)
    float* __restrict__ skip_f32,               // [T][256] f32 (in-place +=)
    const unsigned short* __restrict__ A_dil,   // [3][1024][512] fp16
    const unsigned short* __restrict__ Wres,    // [512][512] fp16
    const unsigned short* __restrict__ Wskip,   // [256][512] fp16
    const float* __restrict__ cond,             // [1024][32] (b_dil+b_cond folded)
    const float* __restrict__ b_res,            // [512]
    const float* __restrict__ b_skip,           // [256]
    int dilation) {
  __shared__ unsigned short preT[64][520];      // 66,560 B; row 16B-aligned
  const int tid = threadIdx.x;
  const int w = tid >> 6, l = tid & 63;
  const int lr = l & 15, lc = l >> 4;
  const int tb = blockIdx.x << 6;
  const int e  = tb >> 9;                        // embedding column (constant per block)

  // ---- phase 1: dilated conv GEMM, K = 3 taps x 512 ----
  f32x4 acc[2][4][4];
  #pragma unroll
  for (int fg=0; fg<2; ++fg)
    #pragma unroll
    for (int mf=0; mf<4; ++mf)
      #pragma unroll
      for (int nf=0; nf<4; ++nf) acc[fg][mf][nf] = {0.f,0.f,0.f,0.f};

  #pragma unroll
  for (int tap=0; tap<3; ++tap) {
    const int shift = (2-tap)*dilation;
    int tg[4];
    #pragma unroll
    for (int nf=0;nf<4;++nf) tg[nf] = tb + 16*nf + lr - shift;
    for (int kc=0; kc<512; kc+=32) {
      f16x8 b[4];
      #pragma unroll
      for (int nf=0;nf<4;++nf)
        b[nf] = ldh_guard(&h_in[(size_t)tg[nf]*512 + kc + lc*8], tg[nf] >= 0);
      const unsigned short* Abase = A_dil + (size_t)tap*1024*512 + kc + lc*8;
      #pragma unroll
      for (int fg=0; fg<2; ++fg) {
        #pragma unroll
        for (int mf=0; mf<4; ++mf) {
          int m = fg*512 + w*64 + mf*16 + lr;
          f16x8 a = ldh(Abase + (size_t)m*512);
          #pragma unroll
          for (int nf=0;nf<4;++nf)
            acc[fg][mf][nf] = __builtin_amdgcn_mfma_f32_16x16x32_f16(a, b[nf], acc[fg][mf][nf], 0,0,0);
        }
      }
    }
  }

  // ---- gating: pre = sigmoid(filter+cond) * tanh(gate+cond) -> LDS (transposed) ----
  #pragma unroll
  for (int mf=0; mf<4; ++mf) {
    #pragma unroll
    for (int nf=0; nf<4; ++nf) {
      int m0 = w*64 + mf*16 + lc*4;
      int n  = nf*16 + lr;
      float pv[4];
      #pragma unroll
      for (int r=0;r<4;++r) {
        int m = m0 + r;
        float f = acc[0][mf][nf][r] + cond[m*32 + e];
        float g = acc[1][mf][nf][r] + cond[(m+512)*32 + e];
        pv[r] = sigmoidf_(f) * tanhf_(g);
      }
      unsigned int* pp = (unsigned int*)&preT[n][m0];
      pp[0] = pack2(pv[0], pv[1]);
      pp[1] = pack2(pv[2], pv[3]);
    }
  }
  __syncthreads();

  // ---- phase 2: res (M=512) + skip (M=256) GEMMs over K=512 of pre ----
  f32x4 racc[4][4];
  f32x4 sacc[2][4];
  #pragma unroll
  for (int mf=0;mf<4;++mf)
    #pragma unroll
    for (int nf=0;nf<4;++nf) racc[mf][nf] = {0.f,0.f,0.f,0.f};
  #pragma unroll
  for (int mf=0;mf<2;++mf)
    #pragma unroll
    for (int nf=0;nf<4;++nf) sacc[mf][nf] = {0.f,0.f,0.f,0.f};

  for (int kc=0; kc<512; kc+=32) {
    f16x8 b[4];
    #pragma unroll
    for (int nf=0;nf<4;++nf)
      b[nf] = ldh(&preT[16*nf+lr][kc + lc*8]);
    #pragma unroll
    for (int mf=0; mf<4; ++mf) {
      f16x8 a = ldh(&Wres[(size_t)(w*64+16*mf+lr)*512 + kc + lc*8]);
      #pragma unroll
      for (int nf=0;nf<4;++nf)
        racc[mf][nf] = __builtin_amdgcn_mfma_f32_16x16x32_f16(a, b[nf], racc[mf][nf], 0,0,0);
    }
    #pragma unroll
    for (int mf=0; mf<2; ++mf) {
      f16x8 a = ldh(&Wskip[(size_t)(w*32+16*mf+lr)*512 + kc + lc*8]);
      #pragma unroll
      for (int nf=0;nf<4;++nf)
        sacc[mf][nf] = __builtin_amdgcn_mfma_f32_16x16x32_f16(a, b[nf], sacc[mf][nf], 0,0,0);
    }
  }

  // ---- epilogue: h += res (+b_res), write fp16 pong; skip += (+b_skip) ----
  #pragma unroll
  for (int mf=0;mf<4;++mf)
    #pragma unroll
    for (int nf=0;nf<4;++nf) {
      int m0 = w*64+16*mf+4*lc;
      int t  = tb + 16*nf + lr;
      f32x4* hp = (f32x4*)&h_f32[(size_t)t*512 + m0];
      f32x4 hv = *hp;
      #pragma unroll
      for (int r=0;r<4;++r) hv[r] += racc[mf][nf][r] + b_res[m0+r];
      *hp = hv;
      unsigned int* hb = (unsigned int*)&h_out[(size_t)t*512 + m0];
      hb[0] = pack2(hv[0],hv[1]); hb[1] = pack2(hv[2],hv[3]);
    }
  #pragma unroll
  for (int mf=0;mf<2;++mf)
    #pragma unroll
    for (int nf=0;nf<4;++nf) {
      int s0 = w*32+16*mf+4*lc;
      int t  = tb + 16*nf + lr;
      f32x4* sp = (f32x4*)&skip_f32[(size_t)t*256 + s0];
      f32x4 sv = *sp;
      #pragma unroll
      for (int r=0;r<4;++r) sv[r] += sacc[mf][nf][r] + b_skip[s0+r];
      *sp = sv;
    }
}

// ---------------- final head: out = Wq @ relu(Wfs @ relu(skip) + b_fs + fcond) + b_q ----
__global__ __launch_bounds__(512) void final_kernel(
    const float* __restrict__ skip_f32, const unsigned short* __restrict__ Wfs,
    const float* __restrict__ b_fskip, const float* __restrict__ fcond,
    const unsigned short* __restrict__ Wq, const float* __restrict__ b_quant,
    float* __restrict__ out) {
  __shared__ unsigned short S1[64][264];
  __shared__ unsigned short S2[64][264];
  int tid=threadIdx.x, w=tid>>6, l=tid&63, lr=l&15, lc=l>>4;
  int tb = blockIdx.x<<6, e = tb>>9;

  // stage relu(skip) as fp16
  for (int j = tid; j < 64*64; j += 512) {
    int r  = j >> 6;
    int c4 = (j & 63) << 2;
    f32x4 v = *(const f32x4*)&skip_f32[(size_t)(tb+r)*256 + c4];
    #pragma unroll
    for (int q=0;q<4;++q) v[q] = fmaxf(v[q], 0.f);
    unsigned int* sp = (unsigned int*)&S1[r][c4];
    sp[0] = pack2(v[0],v[1]); sp[1] = pack2(v[2],v[3]);
  }
  __syncthreads();

  f32x4 acc[2][4];
  #pragma unroll
  for (int mf=0;mf<2;++mf)
    #pragma unroll
    for (int nf=0;nf<4;++nf) acc[mf][nf] = {0.f,0.f,0.f,0.f};
  for (int kc=0;kc<256;kc+=32) {
    f16x8 b[4];
    #pragma unroll
    for (int nf=0;nf<4;++nf) b[nf] = ldh(&S1[16*nf+lr][kc + lc*8]);
    #pragma unroll
    for (int mf=0;mf<2;++mf) {
      f16x8 a = ldh(&Wfs[(size_t)(w*32+16*mf+lr)*256 + kc + lc*8]);
      #pragma unroll
      for (int nf=0;nf<4;++nf)
        acc[mf][nf] = __builtin_amdgcn_mfma_f32_16x16x32_f16(a, b[nf], acc[mf][nf], 0,0,0);
    }
  }
  #pragma unroll
  for (int mf=0;mf<2;++mf)
    #pragma unroll
    for (int nf=0;nf<4;++nf) {
      int m0 = w*32+16*mf+4*lc;
      int n  = 16*nf+lr;
      float pv[4];
      #pragma unroll
      for (int r=0;r<4;++r) {
        float v = acc[mf][nf][r] + b_fskip[m0+r] + fcond[(m0+r)*32 + e];
        pv[r] = fmaxf(v, 0.f);
      }
      unsigned int* pp = (unsigned int*)&S2[n][m0];
      pp[0] = pack2(pv[0],pv[1]); pp[1] = pack2(pv[2],pv[3]);
    }
  __syncthreads();

  f32x4 acc2[2][4];
  #pragma unroll
  for (int mf=0;mf<2;++mf)
    #pragma unroll
    for (int nf=0;nf<4;++nf) acc2[mf][nf] = {0.f,0.f,0.f,0.f};
  for (int kc=0;kc<256;kc+=32) {
    f16x8 b[4];
    #pragma unroll
    for (int nf=0;nf<4;++nf) b[nf] = ldh(&S2[16*nf+lr][kc + lc*8]);
    #pragma unroll
    for (int mf=0;mf<2;++mf) {
      f16x8 a = ldh(&Wq[(size_t)(w*32+16*mf+lr)*256 + kc + lc*8]);
      #pragma unroll
      for (int nf=0;nf<4;++nf)
        acc2[mf][nf] = __builtin_amdgcn_mfma_f32_16x16x32_f16(a, b[nf], acc2[mf][nf], 0,0,0);
    }
  }
  #pragma unroll
  for (int mf=0;mf<2;++mf)
    #pragma unroll
    for (int nf=0;nf<4;++nf) {
      int q0 = w*32+16*mf+4*lc;
      int t  = tb + 16*nf + lr;
      #pragma unroll
      for (int r=0;r<4;++r)
        out[(size_t)(q0+r)*TLEN + t] = acc2[mf][nf][r] + b_quant[q0+r];
    }
}

// ---------------- host ----------------

extern "C" void kernel_launch(void* const* d_in, const int* in_sizes, int n_in,
                              void* d_out, int out_size, void* d_ws, size_t ws_size,
                              hipStream_t stream) {
  const float* x       = (const float*)d_in[0];
  const float* emb     = (const float*)d_in[1];
  const float* w_init  = (const float*)d_in[2];
  const float* b_init  = (const float*)d_in[3];
  const float* w_iskip = (const float*)d_in[4];
  const float* b_iskip = (const float*)d_in[5];
  const float* w_dil   = (const float*)d_in[6];
  const float* b_dil   = (const float*)d_in[7];
  const float* w_cond  = (const float*)d_in[8];
  const float* b_cond  = (const float*)d_in[9];
  const float* w_res   = (const float*)d_in[10];
  const float* b_res   = (const float*)d_in[11];
  const float* w_skip  = (const float*)d_in[12];
  const float* b_skip  = (const float*)d_in[13];
  const float* w_fskip = (const float*)d_in[14];
  const float* b_fskip = (const float*)d_in[15];
  const float* w_fcond = (const float*)d_in[16];
  const float* b_fcond = (const float*)d_in[17];
  const float* w_quant = (const float*)d_in[18];
  const float* b_quant = (const float*)d_in[19];
  float* out = (float*)d_out;

  char* ws = (char*)d_ws;
  size_t off = 0;
  auto carve = [&](size_t bytes) -> void* {
    void* p = ws + off;
    off += (bytes + 255) & ~(size_t)255;
    return p;
  };
  unsigned short* A_dil     = (unsigned short*)carve((size_t)NSTACK*3*1024*512*2);  // 94.4 MB
  unsigned short* Wres_h    = (unsigned short*)carve((size_t)NSTACK*512*512*2);     // 15.7 MB
  unsigned short* Wskip_h   = (unsigned short*)carve((size_t)NSTACK*256*512*2);     //  7.9 MB
  unsigned short* Wiskip_h  = (unsigned short*)carve((size_t)256*512*2);
  unsigned short* Wfskip_h  = (unsigned short*)carve((size_t)256*256*2);
  unsigned short* Wquant_h  = (unsigned short*)carve((size_t)256*256*2);
  float*          h_f32     = (float*)carve((size_t)TLEN*512*4);                    // 33.6 MB
  unsigned short* h_h16     = (unsigned short*)carve((size_t)2*TLEN*512*2);         // 33.6 MB (ping/pong)
  float*          skip_f32  = (float*)carve((size_t)TLEN*256*4);                    // 16.8 MB
  float*          cond_all  = (float*)carve((size_t)NSTACK*1024*32*4);              //  3.9 MB
  float*          fcond_all = (float*)carve((size_t)256*32*4);
  if (off > ws_size) return;  // workspace too small; bail

  // weight conversion
  cast_f16_kernel<<<(NSTACK*512*512/4 + 255)/256, 256, 0, stream>>>(w_res,   Wres_h,   NSTACK*512*512/4);
  cast_f16_kernel<<<(NSTACK*256*512/4 + 255)/256, 256, 0, stream>>>(w_skip,  Wskip_h,  NSTACK*256*512/4);
  cast_f16_kernel<<<(256*512/4 + 255)/256,        256, 0, stream>>>(w_iskip, Wiskip_h, 256*512/4);
  cast_f16_kernel<<<(256*256/4 + 255)/256,        256, 0, stream>>>(w_fskip, Wfskip_h, 256*256/4);
  cast_f16_kernel<<<(256*256/4 + 255)/256,        256, 0, stream>>>(w_quant, Wquant_h, 256*256/4);
  transpose_wdil_kernel<<<(NSTACK*1024*512 + 255)/256, 256, 0, stream>>>(w_dil, A_dil);
  cond_kernel<<<(NSTACK*1024 + 256 + 255)/256, 256, 0, stream>>>(
      emb, w_cond, b_cond, b_dil, w_fcond, b_fcond, cond_all, fcond_all);

  // init conv + init skip
  h0_kernel<<<TLEN*128/256, 256, 0, stream>>>(x, w_init, b_init, h_f32, h_h16);
  skip_init_kernel<<<TLEN/64, 512, 0, stream>>>(h_h16, Wiskip_h, b_iskip, skip_f32);

  // 30 residual layers
  const size_t HB = (size_t)TLEN*512;
  for (int i = 0; i < NSTACK; ++i) {
    int d = 1 << (i % 10);
    layer_kernel<<<TLEN/64, 512, 0, stream>>>(
        h_h16 + (size_t)(i & 1)*HB,
        h_h16 + (size_t)((i + 1) & 1)*HB,
        h_f32, skip_f32,
        A_dil + (size_t)i*3*1024*512,
        Wres_h + (size_t)i*512*512,
        Wskip_h + (size_t)i*256*512,
        cond_all + (size_t)i*1024*32,
        b_res + (size_t)i*512,
        b_skip + (size_t)i*256,
        d);
  }

  // head
  final_kernel<<<TLEN/64, 512, 0, stream>>>(
      skip_f32, Wfskip_h, b_fskip, fcond_all, Wquant_h, b_quant, out);
}